// Round 11
// baseline (4175.970 us; speedup 1.0000x reference)
//
#include <hip/hip_runtime.h>

#define HDIM   256
#define NLAYER 10
#define BATCH  256
#define TSTEPS 512
#define NTHR   512
#define DEPTH  8
#define NWG    176               // 16 slices x (1 feed + 10 layers)

typedef __attribute__((ext_vector_type(8))) short short8;
typedef __attribute__((ext_vector_type(4))) float f32x4;
typedef __attribute__((ext_vector_type(4))) unsigned u32x4;

// ---------- bf16 helpers ----------
__device__ __forceinline__ unsigned short bf16_rne(float f) {
    unsigned v = __float_as_uint(f);
    unsigned r = v + 0x7FFFu + ((v >> 16) & 1u);
    return (unsigned short)(r >> 16);
}
__device__ __forceinline__ float bf16_f(unsigned short b) {
    return __uint_as_float(((unsigned)b) << 16);
}
__device__ __forceinline__ float fast_tanh(float v) {
    float a = fabsf(v);
    float e = __expf(-2.0f * a);
    float r = (1.0f - e) / (1.0f + e);
    return __builtin_copysignf(r, v);
}
__device__ __forceinline__ void cvt8(const float* __restrict__ p, short8& hi, short8& lo) {
#pragma unroll
    for (int e = 0; e < 8; ++e) {
        float f = p[e];
        unsigned short h = bf16_rne(f);
        hi[e] = (short)h;
        lo[e] = (short)bf16_rne(f - bf16_f(h));
    }
}

#define MFMA16(a, b, c) __builtin_amdgcn_mfma_f32_16x16x32_bf16((a), (b), (c), 0, 0, 0)

__device__ __forceinline__ void wait_ge(int* f, int need) {
    while (__hip_atomic_load(f, __ATOMIC_RELAXED, __HIP_MEMORY_SCOPE_AGENT) < need)
        __builtin_amdgcn_s_sleep(1);
}
#define AT_LD(p)    __hip_atomic_load((p), __ATOMIC_RELAXED, __HIP_MEMORY_SCOPE_AGENT)
#define AT_ST(p, v) __hip_atomic_store((p), (v), __ATOMIC_RELAXED, __HIP_MEMORY_SCOPE_AGENT)
#define VMDRAIN()   asm volatile("s_waitcnt vmcnt(0)" ::: "memory")
#define PKF(a, b)   (((unsigned long long)__float_as_uint(b) << 32) | __float_as_uint(a))

// LDS byte layout (144 KB):
#define WXH 0        // Wx_{l+1} hi swizzled [c 256][k 256] bf16 : 131072
#define HHI 131072   // h(t-1) hi [row 16][k 256], swizzled      :   8192
#define HLO 139264   // h(t-1) lo                                :   8192

__device__ __forceinline__ void stage_whi_f32(const float* __restrict__ src, char* smem, int tid) {
    for (int i = 0; i < 16; ++i) {
        const int ch = tid + i * NTHR;
        const int r = ch >> 5, kb = ch & 31;
        short8 hi, lo;
        cvt8(src + (size_t)r * HDIM + kb * 8, hi, lo);
        *(short8*)(smem + r * 512 + ((kb * 16) ^ ((r & 7) << 4))) = hi;
    }
}

// u-buffer store: fast (plain, coalesced, shared-L2) or remote (sc1 atomics)
__device__ __forceinline__ void u_store(char* us, bool loc,
                                        const f32x4& a0, const f32x4& a1,
                                        float b0, float b1) {
    if (loc) {
        u32x4 sa = { __float_as_uint(a0[0] + b0), __float_as_uint(a0[1] + b0),
                     __float_as_uint(a0[2] + b0), __float_as_uint(a0[3] + b0) };
        u32x4 sb = { __float_as_uint(a1[0] + b1), __float_as_uint(a1[1] + b1),
                     __float_as_uint(a1[2] + b1), __float_as_uint(a1[3] + b1) };
        *(u32x4*)us = sa;
        *(u32x4*)(us + 16) = sb;
    } else {
        unsigned long long* q = (unsigned long long*)us;
        AT_ST(q + 0, PKF(a0[0] + b0, a0[1] + b0));
        AT_ST(q + 1, PKF(a0[2] + b0, a0[3] + b0));
        AT_ST(q + 2, PKF(a1[0] + b1, a1[1] + b1));
        AT_ST(q + 3, PKF(a1[2] + b1, a1[3] + b1));
    }
}

// wg placement: bid = (s&7) + 8*(lp + 11*(s>>3)); lp=0 feed, lp=1..10 -> layer lp-1.
// All 11 wgs of a slice share bid%8 -> same XCD under round-robin dispatch; verified
// at runtime via XCC_ID table, with sc1-atomic fallback per producer/consumer pair.
__global__ void __launch_bounds__(NTHR) rnn_pipe(
    const int* __restrict__ tokens, const float* __restrict__ hidden0,
    const float* __restrict__ emb,
    const float* __restrict__ Wx_w, const float* __restrict__ Wx_b,
    const float* __restrict__ Wh_w, const float* __restrict__ Wh_b,
    float* __restrict__ u,            // [10][16][DEPTH][4096] fp32, tid-linear frags
    int* __restrict__ fu,             // [10][16][TSTEPS]
    int* __restrict__ fd,             // [16][TSTEPS]
    int* __restrict__ xcct,           // [256]: [bid]=xcc+1; [192]=arrival counter
    float* __restrict__ out) {
    const int bid = blockIdx.x;
    const int tid = threadIdx.x;
    const int wv = tid >> 6;
    const int lane = tid & 63;
    const int ln15 = lane & 15;
    const int kq = (lane >> 4) << 3;
    const int hi16 = (lane >> 4) << 4;
    const int swz = (ln15 & 7) << 4;
    const int srow = tid >> 5;
    const int scb = tid & 31;

    const int x8 = bid & 7, jj = bid >> 3, sh = jj / 11, lp = jj % 11;
    const int s16 = x8 + (sh << 3);
    const bool isFeed = (lp == 0);
    const int l = lp - 1;

    __shared__ char smem[147456];
    float* hfinal = out + (size_t)BATCH * TSTEPS * HDIM;

    // ---- XCC handshake (publish my XCD; all-wg rendezvous) ----
    unsigned my_xcc;
    asm volatile("s_getreg_b32 %0, hwreg(HW_REG_XCC_ID)" : "=s"(my_xcc));
    if (tid == 0) {
        AT_ST(xcct + bid, (int)my_xcc + 1);
        __hip_atomic_fetch_add(xcct + 192, 1, __ATOMIC_RELEASE, __HIP_MEMORY_SCOPE_AGENT);
    }

    if (!isFeed) {
        // ================= REC (layer l, slice s16) =================
        const bool ship = (l < NLAYER - 1);

        if (ship) stage_whi_f32(Wx_w + (size_t)(l + 1) * 65536, smem, tid);
        short8 whh[2][8], whl[2][8], wxl[2][8];
        {
            const float* whsrc = Wh_w + (size_t)l * 65536;
            const float* wxsrc = Wx_w + (size_t)(l + 1) * 65536;
#define WINIT(ni, kc) do { \
            cvt8(whsrc + (size_t)(wv * 32 + ni * 16 + ln15) * HDIM + kc * 32 + kq, whh[ni][kc], whl[ni][kc]); \
            if (ship) { short8 _d; \
                cvt8(wxsrc + (size_t)(wv * 32 + ni * 16 + ln15) * HDIM + kc * 32 + kq, _d, wxl[ni][kc]); } \
            else { wxl[ni][kc] = short8{0,0,0,0,0,0,0,0}; } \
            asm volatile("" : "+v"(whh[ni][kc]), "+v"(whl[ni][kc]), "+v"(wxl[ni][kc])); \
        } while (0)
            WINIT(0,0); WINIT(0,1); WINIT(0,2); WINIT(0,3);
            WINIT(0,4); WINIT(0,5); WINIT(0,6); WINIT(0,7);
            WINIT(1,0); WINIT(1,1); WINIT(1,2); WINIT(1,3);
            WINIT(1,4); WINIT(1,5); WINIT(1,6); WINIT(1,7);
#undef WINIT
        }
        {
            short8 hi, lo;
            cvt8(hidden0 + ((size_t)(l * BATCH + s16 * 16 + srow)) * HDIM + scb * 8, hi, lo);
            const int so = srow * 512 + ((scb * 16) ^ ((srow & 7) << 4));
            *(short8*)(smem + HHI + so) = hi;
            *(short8*)(smem + HLO + so) = lo;
        }
        float bvn[2] = { 0.f, 0.f };
        if (ship) {
#pragma unroll
            for (int ni = 0; ni < 2; ++ni) {
                const int col = wv * 32 + ni * 16 + ln15;
                bvn[ni] = Wx_b[(l + 1) * HDIM + col] + Wh_b[(l + 1) * HDIM + col];
            }
        }

        int* fuMe = fu + ((size_t)l * 16 + s16) * TSTEPS;
        int* fuNx = ship ? fu + ((size_t)(l + 1) * 16 + s16) * TSTEPS : nullptr;
        int* fuG  = (l < NLAYER - 2) ? fu + ((size_t)(l + 2) * 16 + s16) * TSTEPS : nullptr;
        int* fdA  = fd + (size_t)s16 * TSTEPS;
        const char* myu = (const char*)(u + ((size_t)l * 16 + s16) * DEPTH * 4096);
        char* nxu = ship ? (char*)(u + ((size_t)(l + 1) * 16 + s16) * DEPTH * 4096) : nullptr;

        // rendezvous + pair locality
        if (tid == 0) wait_ge(xcct + 192, NWG);
        __syncthreads();
        const int pbid = x8 + 8 * (l + 11 * sh);           // my u producer
        const int cbid = x8 + 8 * ((l + 2) + 11 * sh);     // my u-ship consumer
        const bool locP = (AT_LD(xcct + pbid) == (int)my_xcc + 1);
        const bool locC = ship ? (AT_LD(xcct + cbid) == (int)my_xcc + 1) : false;

        for (int t = 0; t < TSTEPS; ++t) {
            if (tid == 0) wait_ge(fuMe + t, 1);
            if (tid == 64 && ship) {
                if (l < NLAYER - 2) { if (t >= 11) wait_ge(fuG + (t - 11), 1); }
                else                { if (t >= 9)  wait_ge(fdA + (t - 9), 1); }
            }
            __syncthreads();

            // A: u_l(t) loads — fast: sc0 L1-bypass from shared L2; remote: sc1
            u32x4 la = {}, lb = {};
            unsigned long long q0 = 0, q1 = 0, q2 = 0, q3 = 0;
            const char* up = myu + ((size_t)(t & 7) << 14) + ((size_t)tid << 5);
            if (locP) {
                asm volatile("global_load_dwordx4 %0, %2, off sc0\n\t"
                             "global_load_dwordx4 %1, %2, off offset:16 sc0"
                             : "=&v"(la), "=&v"(lb) : "v"(up) : "memory");
            } else {
                const unsigned long long* upq = (const unsigned long long*)up;
                q0 = AT_LD(upq); q1 = AT_LD(upq + 1); q2 = AT_LD(upq + 2); q3 = AT_LD(upq + 3);
            }

            // B: acc_h = h(t-1)@Wh; acc_u = h(t-1)@Wx_{l+1}
            const bool doU = ship && (t >= 1);
            f32x4 ah0a = {}, ah0b = {}, ah1a = {}, ah1b = {};
            f32x4 au0 = {}, au1 = {};
#define HX_KC(kc, A0, A1) do { \
            const int _off = ((kc) * 64 + hi16) ^ swz; \
            const short8 hh = *(const short8*)(smem + HHI + ln15 * 512 + _off); \
            const short8 hl = *(const short8*)(smem + HLO + ln15 * 512 + _off); \
            A0 = MFMA16(hh, whh[0][kc], A0);  A1 = MFMA16(hh, whh[1][kc], A1); \
            A0 = MFMA16(hh, whl[0][kc], A0);  A1 = MFMA16(hh, whl[1][kc], A1); \
            A0 = MFMA16(hl, whh[0][kc], A0);  A1 = MFMA16(hl, whh[1][kc], A1); \
            if (doU) { \
                const short8 bh0 = *(const short8*)(smem + WXH + (wv * 32 + ln15) * 512 + _off); \
                const short8 bh1 = *(const short8*)(smem + WXH + (wv * 32 + 16 + ln15) * 512 + _off); \
                au0 = MFMA16(hh, bh0, au0);         au1 = MFMA16(hh, bh1, au1); \
                au0 = MFMA16(hh, wxl[0][kc], au0);  au1 = MFMA16(hh, wxl[1][kc], au1); \
                au0 = MFMA16(hl, bh0, au0);         au1 = MFMA16(hl, bh1, au1); \
            } \
        } while (0)
            HX_KC(0, ah0a, ah1a); HX_KC(1, ah0a, ah1a);
            HX_KC(2, ah0a, ah1a); HX_KC(3, ah0a, ah1a);
            HX_KC(4, ah0b, ah1b); HX_KC(5, ah0b, ah1b);
            HX_KC(6, ah0b, ah1b); HX_KC(7, ah0b, ah1b);
#undef HX_KC

            VMDRAIN();                               // u loads arrived; prior stores acked
            __builtin_amdgcn_sched_barrier(0);       // rule #18: no use-hoist past drain
            __syncthreads();                         // LDS h reads complete

            if (tid == 0) {
                if (ship && t >= 2) AT_ST(fuNx + (t - 2), 1);
                if (!ship) AT_ST(fdA + t, 1);
            }
            f32x4 uva, uvb;
            if (locP) {
                uva = f32x4{ __uint_as_float(la[0]), __uint_as_float(la[1]),
                             __uint_as_float(la[2]), __uint_as_float(la[3]) };
                uvb = f32x4{ __uint_as_float(lb[0]), __uint_as_float(lb[1]),
                             __uint_as_float(lb[2]), __uint_as_float(lb[3]) };
            } else {
                uva = f32x4{ __uint_as_float((unsigned)q0), __uint_as_float((unsigned)(q0 >> 32)),
                             __uint_as_float((unsigned)q1), __uint_as_float((unsigned)(q1 >> 32)) };
                uvb = f32x4{ __uint_as_float((unsigned)q2), __uint_as_float((unsigned)(q2 >> 32)),
                             __uint_as_float((unsigned)q3), __uint_as_float((unsigned)(q3 >> 32)) };
            }
            unsigned pk[2][4];
#pragma unroll
            for (int r = 0; r < 4; ++r) {
                const float y0 = fast_tanh(ah0a[r] + ah0b[r] + uva[r]);
                const float y1 = fast_tanh(ah1a[r] + ah1b[r] + uvb[r]);
                unsigned short h0 = bf16_rne(y0), h1 = bf16_rne(y1);
                pk[0][r] = (unsigned)h0 | ((unsigned)bf16_rne(y0 - bf16_f(h0)) << 16);
                pk[1][r] = (unsigned)h1 | ((unsigned)bf16_rne(y1 - bf16_f(h1)) << 16);
            }
#pragma unroll
            for (int ni = 0; ni < 2; ++ni) {
                const int col = wv * 32 + ni * 16 + ln15;
#pragma unroll
                for (int r = 0; r < 4; ++r) {
                    const int row = ((lane >> 4) << 2) + r;
                    const int so = row * 512 + ((2 * col) ^ ((row & 7) << 4));
                    *(unsigned short*)(smem + HHI + so) = (unsigned short)(pk[ni][r] & 0xffffu);
                    *(unsigned short*)(smem + HLO + so) = (unsigned short)(pk[ni][r] >> 16);
                    if (!ship) {
                        const float y = bf16_f((unsigned short)(pk[ni][r] & 0xffffu)) +
                                        bf16_f((unsigned short)(pk[ni][r] >> 16));
                        out[((size_t)(s16 * 16 + row) * TSTEPS + t) * HDIM + col] = y;
                    }
                    if (t == TSTEPS - 1) {
                        const float y = bf16_f((unsigned short)(pk[ni][r] & 0xffffu)) +
                                        bf16_f((unsigned short)(pk[ni][r] >> 16));
                        hfinal[((size_t)l * BATCH + s16 * 16 + row) * HDIM + col] = y;
                    }
                }
            }
            if (doU)
                u_store(nxu + ((size_t)((t - 1) & 7) << 14) + ((size_t)tid << 5),
                        locC, au0, au1, bvn[0], bvn[1]);
        }

        // epilogue: ship u_{l+1}(511)
        if (ship) {
            if (tid == 64) {
                if (l < NLAYER - 2) wait_ge(fuG + 501, 1);
                else                wait_ge(fdA + 503, 1);
            }
            __syncthreads();
            f32x4 au0 = {}, au1 = {};
#define UE_KC(kc) do { \
            const int _off = ((kc) * 64 + hi16) ^ swz; \
            const short8 hh = *(const short8*)(smem + HHI + ln15 * 512 + _off); \
            const short8 hl = *(const short8*)(smem + HLO + ln15 * 512 + _off); \
            const short8 bh0 = *(const short8*)(smem + WXH + (wv * 32 + ln15) * 512 + _off); \
            const short8 bh1 = *(const short8*)(smem + WXH + (wv * 32 + 16 + ln15) * 512 + _off); \
            au0 = MFMA16(hh, bh0, au0);         au1 = MFMA16(hh, bh1, au1); \
            au0 = MFMA16(hh, wxl[0][kc], au0);  au1 = MFMA16(hh, wxl[1][kc], au1); \
            au0 = MFMA16(hl, bh0, au0);         au1 = MFMA16(hl, bh1, au1); \
        } while (0)
            UE_KC(0); UE_KC(1); UE_KC(2); UE_KC(3);
            UE_KC(4); UE_KC(5); UE_KC(6); UE_KC(7);
#undef UE_KC
            u_store(nxu + ((size_t)(511 & 7) << 14) + ((size_t)tid << 5),
                    locC, au0, au1, bvn[0], bvn[1]);
            VMDRAIN();
            __syncthreads();
            if (tid == 0) {
                AT_ST(fuNx + 510, 1);
                AT_ST(fuNx + 511, 1);
            }
        }
    } else {
        // ================= FEED (layer-0 u producer, slice s16) =================
        stage_whi_f32(Wx_w, smem, tid);
        short8 wxl[2][8];
#define FWINIT(ni, kc) do { \
        short8 _d; \
        cvt8(Wx_w + (size_t)(wv * 32 + ni * 16 + ln15) * HDIM + kc * 32 + kq, _d, wxl[ni][kc]); \
        asm volatile("" : "+v"(wxl[ni][kc])); \
    } while (0)
        FWINIT(0,0); FWINIT(0,1); FWINIT(0,2); FWINIT(0,3);
        FWINIT(0,4); FWINIT(0,5); FWINIT(0,6); FWINIT(0,7);
        FWINIT(1,0); FWINIT(1,1); FWINIT(1,2); FWINIT(1,3);
        FWINIT(1,4); FWINIT(1,5); FWINIT(1,6); FWINIT(1,7);
#undef FWINIT
        float b0[2];
#pragma unroll
        for (int ni = 0; ni < 2; ++ni) {
            const int col = wv * 32 + ni * 16 + ln15;
            b0[ni] = Wx_b[col] + Wh_b[col];
        }
        int* fuMe = fu + (size_t)s16 * TSTEPS;
        int* fuG  = fu + ((size_t)16 + s16) * TSTEPS;
        char* nxu = (char*)(u + (size_t)s16 * DEPTH * 4096);

        if (tid == 0) wait_ge(xcct + 192, NWG);
        __syncthreads();
        const int cbid = x8 + 8 * (1 + 11 * sh);
        const bool locC = (AT_LD(xcct + cbid) == (int)my_xcc + 1);

        for (int t = 0; t < TSTEPS; ++t) {
            if (tid == 0 && t >= 10) wait_ge(fuG + (t - 10), 1);
            __syncthreads();
            {
                const int tok = tokens[(s16 * 16 + srow) * TSTEPS + t];
                short8 hi, lo;
                cvt8(emb + (size_t)tok * HDIM + scb * 8, hi, lo);
                const int so = srow * 512 + ((scb * 16) ^ ((srow & 7) << 4));
                *(short8*)(smem + HHI + so) = hi;
                *(short8*)(smem + HLO + so) = lo;
            }
            __syncthreads();
            f32x4 ax0 = {}, ax1 = {};
#define FX_KC(kc) do { \
            const int _off = ((kc) * 64 + hi16) ^ swz; \
            const short8 xh = *(const short8*)(smem + HHI + ln15 * 512 + _off); \
            const short8 xl = *(const short8*)(smem + HLO + ln15 * 512 + _off); \
            const short8 bh0 = *(const short8*)(smem + WXH + (wv * 32 + ln15) * 512 + _off); \
            const short8 bh1 = *(const short8*)(smem + WXH + (wv * 32 + 16 + ln15) * 512 + _off); \
            ax0 = MFMA16(xh, bh0, ax0);         ax1 = MFMA16(xh, bh1, ax1); \
            ax0 = MFMA16(xh, wxl[0][kc], ax0);  ax1 = MFMA16(xh, wxl[1][kc], ax1); \
            ax0 = MFMA16(xl, bh0, ax0);         ax1 = MFMA16(xl, bh1, ax1); \
        } while (0)
            FX_KC(0); FX_KC(1); FX_KC(2); FX_KC(3);
            FX_KC(4); FX_KC(5); FX_KC(6); FX_KC(7);
#undef FX_KC
            u_store(nxu + ((size_t)(t & 7) << 14) + ((size_t)tid << 5),
                    locC, ax0, ax1, b0[0], b0[1]);
            VMDRAIN();
            __syncthreads();
            if (tid == 0) AT_ST(fuMe + t, 1);
        }
    }
}

// ---------- host ----------
extern "C" void kernel_launch(void* const* d_in, const int* in_sizes, int n_in,
                              void* d_out, int out_size, void* d_ws, size_t ws_size,
                              hipStream_t stream) {
    const int* tokens = (const int*)d_in[0];
    const float* hidden0 = (const float*)d_in[1];
    const float* emb = (const float*)d_in[2];
    const float* Wx_w = (const float*)d_in[3];
    const float* Wx_b = (const float*)d_in[4];
    const float* Wh_w = (const float*)d_in[5];
    const float* Wh_b = (const float*)d_in[6];
    float* out = (float*)d_out;

    char* ws = (char*)d_ws;
    size_t off = 0;
    auto carve = [&](size_t bytes) -> void* {
        void* p = ws + off;
        off = (off + bytes + 255) & ~(size_t)255;
        return p;
    };
    float* u = (float*)carve((size_t)NLAYER * 16 * DEPTH * 4096 * 4);  // 20.97 MB
    int* fu = (int*)carve((size_t)NLAYER * 16 * TSTEPS * 4);           // 327680 B
    int* fd = (int*)carve((size_t)16 * TSTEPS * 4);                    // 32768 B
    int* xcct = (int*)carve(1024);                                     // 1024 B
    (void)ws_size; (void)in_sizes; (void)n_in; (void)out_size;

    // fu, fd, xcct are contiguous 256-multiples: one memset
    hipMemsetAsync(fu, 0, (size_t)327680 + 32768 + 1024, stream);

    void* args[] = { (void*)&tokens, (void*)&hidden0, (void*)&emb,
                     (void*)&Wx_w, (void*)&Wx_b, (void*)&Wh_w, (void*)&Wh_b,
                     (void*)&u, (void*)&fu, (void*)&fd, (void*)&xcct, (void*)&out };
    hipLaunchCooperativeKernel((void*)rnn_pipe, dim3(NWG), dim3(NTHR), args, 0, stream);
}

// Round 12
// 4096.551 us; speedup vs baseline: 1.0194x; 1.0194x over previous
//
#include <hip/hip_runtime.h>

#define HDIM   256
#define NLAYER 10
#define BATCH  256
#define TSTEPS 512
#define NTHR   512
#define DEPTH  8
#define NWG    176               // 16 slices x (1 feed + 10 layers)

typedef __attribute__((ext_vector_type(8))) short short8;
typedef __attribute__((ext_vector_type(4))) float f32x4;
typedef __attribute__((ext_vector_type(4))) unsigned u32x4;

// ---------- bf16 helpers ----------
__device__ __forceinline__ unsigned short bf16_rne(float f) {
    unsigned v = __float_as_uint(f);
    unsigned r = v + 0x7FFFu + ((v >> 16) & 1u);
    return (unsigned short)(r >> 16);
}
__device__ __forceinline__ float bf16_f(unsigned short b) {
    return __uint_as_float(((unsigned)b) << 16);
}
__device__ __forceinline__ float fast_tanh(float v) {
    float a = fabsf(v);
    float e = __expf(-2.0f * a);
    float r = (1.0f - e) / (1.0f + e);
    return __builtin_copysignf(r, v);
}
__device__ __forceinline__ void cvt8(const float* __restrict__ p, short8& hi, short8& lo) {
#pragma unroll
    for (int e = 0; e < 8; ++e) {
        float f = p[e];
        unsigned short h = bf16_rne(f);
        hi[e] = (short)h;
        lo[e] = (short)bf16_rne(f - bf16_f(h));
    }
}
// nt variant: keeps streaming emb rows out of L2
__device__ __forceinline__ void cvt8_nt(const float* __restrict__ p, short8& hi, short8& lo) {
#pragma unroll
    for (int e = 0; e < 8; ++e) {
        float f = __builtin_nontemporal_load(p + e);
        unsigned short h = bf16_rne(f);
        hi[e] = (short)h;
        lo[e] = (short)bf16_rne(f - bf16_f(h));
    }
}

#define MFMA16(a, b, c) __builtin_amdgcn_mfma_f32_16x16x32_bf16((a), (b), (c), 0, 0, 0)

__device__ __forceinline__ void wait_ge(int* f, int need) {
    while (__hip_atomic_load(f, __ATOMIC_RELAXED, __HIP_MEMORY_SCOPE_AGENT) < need)
        __builtin_amdgcn_s_sleep(1);
}
#define AT_LD(p)    __hip_atomic_load((p), __ATOMIC_RELAXED, __HIP_MEMORY_SCOPE_AGENT)
#define AT_ST(p, v) __hip_atomic_store((p), (v), __ATOMIC_RELAXED, __HIP_MEMORY_SCOPE_AGENT)
#define VMDRAIN()   asm volatile("s_waitcnt vmcnt(0)" ::: "memory")
#define PKF(a, b)   (((unsigned long long)__float_as_uint(b) << 32) | __float_as_uint(a))

// LDS byte layout (144 KB):
#define WXH 0        // Wx_{l+1} hi swizzled [c 256][k 256] bf16 : 131072
#define HHI 131072   // h(t-1) hi [row 16][k 256], swizzled      :   8192
#define HLO 139264   // h(t-1) lo                                :   8192

__device__ __forceinline__ void stage_whi_f32(const float* __restrict__ src, char* smem, int tid) {
    for (int i = 0; i < 16; ++i) {
        const int ch = tid + i * NTHR;
        const int r = ch >> 5, kb = ch & 31;
        short8 hi, lo;
        cvt8(src + (size_t)r * HDIM + kb * 8, hi, lo);
        *(short8*)(smem + r * 512 + ((kb * 16) ^ ((r & 7) << 4))) = hi;
    }
}

// u-buffer store: fast (plain, coalesced, shared-L2 write-back) or remote (sc1 atomics)
__device__ __forceinline__ void u_store(char* us, bool loc,
                                        const f32x4& a0, const f32x4& a1,
                                        float b0, float b1) {
    if (loc) {
        u32x4 sa = { __float_as_uint(a0[0] + b0), __float_as_uint(a0[1] + b0),
                     __float_as_uint(a0[2] + b0), __float_as_uint(a0[3] + b0) };
        u32x4 sb = { __float_as_uint(a1[0] + b1), __float_as_uint(a1[1] + b1),
                     __float_as_uint(a1[2] + b1), __float_as_uint(a1[3] + b1) };
        *(u32x4*)us = sa;
        *(u32x4*)(us + 16) = sb;
    } else {
        unsigned long long* q = (unsigned long long*)us;
        AT_ST(q + 0, PKF(a0[0] + b0, a0[1] + b0));
        AT_ST(q + 1, PKF(a0[2] + b0, a0[3] + b0));
        AT_ST(q + 2, PKF(a1[0] + b1, a1[1] + b1));
        AT_ST(q + 3, PKF(a1[2] + b1, a1[3] + b1));
    }
}

// wg placement: bid = (s&7) + 8*(lp + 11*(s>>3)); lp=0 feed, lp=1..10 -> layer lp-1.
// All 11 wgs of a slice share bid%8 -> same XCD under round-robin dispatch; verified
// at runtime via XCC_ID table, with sc1-atomic fallback per producer/consumer pair.
__global__ void __launch_bounds__(NTHR) rnn_pipe(
    const int* __restrict__ tokens, const float* __restrict__ hidden0,
    const float* __restrict__ emb,
    const float* __restrict__ Wx_w, const float* __restrict__ Wx_b,
    const float* __restrict__ Wh_w, const float* __restrict__ Wh_b,
    float* __restrict__ u,            // [10][16][DEPTH][4096] fp32, tid-linear frags
    int* __restrict__ fu,             // [10][16][TSTEPS]
    int* __restrict__ fd,             // [16][TSTEPS]
    int* __restrict__ xcct,           // [256]: [bid]=xcc+1; [192]=arrival counter
    float* __restrict__ out) {
    const int bid = blockIdx.x;
    const int tid = threadIdx.x;
    const int wv = tid >> 6;
    const int lane = tid & 63;
    const int ln15 = lane & 15;
    const int kq = (lane >> 4) << 3;
    const int hi16 = (lane >> 4) << 4;
    const int swz = (ln15 & 7) << 4;
    const int srow = tid >> 5;
    const int scb = tid & 31;

    const int x8 = bid & 7, jj = bid >> 3, sh = jj / 11, lp = jj % 11;
    const int s16 = x8 + (sh << 3);
    const bool isFeed = (lp == 0);
    const int l = lp - 1;

    __shared__ char smem[147456];
    float* hfinal = out + (size_t)BATCH * TSTEPS * HDIM;

    // ---- XCC handshake (publish my XCD; all-wg rendezvous) ----
    unsigned my_xcc;
    asm volatile("s_getreg_b32 %0, hwreg(HW_REG_XCC_ID)" : "=s"(my_xcc));
    if (tid == 0) {
        AT_ST(xcct + bid, (int)my_xcc + 1);
        __hip_atomic_fetch_add(xcct + 192, 1, __ATOMIC_RELEASE, __HIP_MEMORY_SCOPE_AGENT);
    }

    if (!isFeed) {
        // ================= REC (layer l, slice s16) =================
        const bool ship = (l < NLAYER - 1);

        if (ship) stage_whi_f32(Wx_w + (size_t)(l + 1) * 65536, smem, tid);
        short8 whh[2][8], whl[2][8], wxl[2][8];
        {
            const float* whsrc = Wh_w + (size_t)l * 65536;
            const float* wxsrc = Wx_w + (size_t)(l + 1) * 65536;
#define WINIT(ni, kc) do { \
            cvt8(whsrc + (size_t)(wv * 32 + ni * 16 + ln15) * HDIM + kc * 32 + kq, whh[ni][kc], whl[ni][kc]); \
            if (ship) { short8 _d; \
                cvt8(wxsrc + (size_t)(wv * 32 + ni * 16 + ln15) * HDIM + kc * 32 + kq, _d, wxl[ni][kc]); } \
            else { wxl[ni][kc] = short8{0,0,0,0,0,0,0,0}; } \
            asm volatile("" : "+v"(whh[ni][kc]), "+v"(whl[ni][kc]), "+v"(wxl[ni][kc])); \
        } while (0)
            WINIT(0,0); WINIT(0,1); WINIT(0,2); WINIT(0,3);
            WINIT(0,4); WINIT(0,5); WINIT(0,6); WINIT(0,7);
            WINIT(1,0); WINIT(1,1); WINIT(1,2); WINIT(1,3);
            WINIT(1,4); WINIT(1,5); WINIT(1,6); WINIT(1,7);
#undef WINIT
        }
        {
            short8 hi, lo;
            cvt8(hidden0 + ((size_t)(l * BATCH + s16 * 16 + srow)) * HDIM + scb * 8, hi, lo);
            const int so = srow * 512 + ((scb * 16) ^ ((srow & 7) << 4));
            *(short8*)(smem + HHI + so) = hi;
            *(short8*)(smem + HLO + so) = lo;
        }
        float bvn[2] = { 0.f, 0.f };
        if (ship) {
#pragma unroll
            for (int ni = 0; ni < 2; ++ni) {
                const int col = wv * 32 + ni * 16 + ln15;
                bvn[ni] = Wx_b[(l + 1) * HDIM + col] + Wh_b[(l + 1) * HDIM + col];
            }
        }

        int* fuMe = fu + ((size_t)l * 16 + s16) * TSTEPS;
        int* fuNx = ship ? fu + ((size_t)(l + 1) * 16 + s16) * TSTEPS : nullptr;
        int* fuG  = (l < NLAYER - 2) ? fu + ((size_t)(l + 2) * 16 + s16) * TSTEPS : nullptr;
        int* fdA  = fd + (size_t)s16 * TSTEPS;
        const char* myu = (const char*)(u + ((size_t)l * 16 + s16) * DEPTH * 4096);
        char* nxu = ship ? (char*)(u + ((size_t)(l + 1) * 16 + s16) * DEPTH * 4096) : nullptr;

        // rendezvous + pair locality
        if (tid == 0) wait_ge(xcct + 192, NWG);
        __syncthreads();
        const int pbid = x8 + 8 * (l + 11 * sh);           // my u producer
        const int cbid = x8 + 8 * ((l + 2) + 11 * sh);     // my u-ship consumer
        const bool locP = (AT_LD(xcct + pbid) == (int)my_xcc + 1);
        const bool locC = ship ? (AT_LD(xcct + cbid) == (int)my_xcc + 1) : false;

        for (int t = 0; t < TSTEPS; ++t) {
            if (tid == 0) wait_ge(fuMe + t, 1);
            if (tid == 64 && ship) {
                if (l < NLAYER - 2) { if (t >= 11) wait_ge(fuG + (t - 11), 1); }
                else                { if (t >= 9)  wait_ge(fdA + (t - 9), 1); }
            }
            __syncthreads();

            // A: u_l(t) loads — fast: sc0 L1-bypass from shared L2; remote: sc1
            u32x4 la = {}, lb = {};
            unsigned long long q0 = 0, q1 = 0, q2 = 0, q3 = 0;
            const char* up = myu + ((size_t)(t & 7) << 14) + ((size_t)tid << 5);
            if (locP) {
                asm volatile("global_load_dwordx4 %0, %2, off sc0\n\t"
                             "global_load_dwordx4 %1, %2, off offset:16 sc0"
                             : "=&v"(la), "=&v"(lb) : "v"(up) : "memory");
            } else {
                const unsigned long long* upq = (const unsigned long long*)up;
                q0 = AT_LD(upq); q1 = AT_LD(upq + 1); q2 = AT_LD(upq + 2); q3 = AT_LD(upq + 3);
            }

            // B: acc_h = h(t-1)@Wh; acc_u = h(t-1)@Wx_{l+1}
            const bool doU = ship && (t >= 1);
            f32x4 ah0a = {}, ah0b = {}, ah1a = {}, ah1b = {};
            f32x4 au0 = {}, au1 = {};
#define HX_KC(kc, A0, A1) do { \
            const int _off = ((kc) * 64 + hi16) ^ swz; \
            const short8 hh = *(const short8*)(smem + HHI + ln15 * 512 + _off); \
            const short8 hl = *(const short8*)(smem + HLO + ln15 * 512 + _off); \
            A0 = MFMA16(hh, whh[0][kc], A0);  A1 = MFMA16(hh, whh[1][kc], A1); \
            A0 = MFMA16(hh, whl[0][kc], A0);  A1 = MFMA16(hh, whl[1][kc], A1); \
            A0 = MFMA16(hl, whh[0][kc], A0);  A1 = MFMA16(hl, whh[1][kc], A1); \
            if (doU) { \
                const short8 bh0 = *(const short8*)(smem + WXH + (wv * 32 + ln15) * 512 + _off); \
                const short8 bh1 = *(const short8*)(smem + WXH + (wv * 32 + 16 + ln15) * 512 + _off); \
                au0 = MFMA16(hh, bh0, au0);         au1 = MFMA16(hh, bh1, au1); \
                au0 = MFMA16(hh, wxl[0][kc], au0);  au1 = MFMA16(hh, wxl[1][kc], au1); \
                au0 = MFMA16(hl, bh0, au0);         au1 = MFMA16(hl, bh1, au1); \
            } \
        } while (0)
            HX_KC(0, ah0a, ah1a); HX_KC(1, ah0a, ah1a);
            HX_KC(2, ah0a, ah1a); HX_KC(3, ah0a, ah1a);
            HX_KC(4, ah0b, ah1b); HX_KC(5, ah0b, ah1b);
            HX_KC(6, ah0b, ah1b); HX_KC(7, ah0b, ah1b);
#undef HX_KC

            VMDRAIN();                               // u loads arrived; prior stores acked
            __builtin_amdgcn_sched_barrier(0);       // rule #18: no use-hoist past drain
            __syncthreads();                         // LDS h reads complete

            if (tid == 0) {
                if (ship && t >= 2) AT_ST(fuNx + (t - 2), 1);
                if (!ship) AT_ST(fdA + t, 1);
            }
            f32x4 uva, uvb;
            if (locP) {
                uva = f32x4{ __uint_as_float(la[0]), __uint_as_float(la[1]),
                             __uint_as_float(la[2]), __uint_as_float(la[3]) };
                uvb = f32x4{ __uint_as_float(lb[0]), __uint_as_float(lb[1]),
                             __uint_as_float(lb[2]), __uint_as_float(lb[3]) };
            } else {
                uva = f32x4{ __uint_as_float((unsigned)q0), __uint_as_float((unsigned)(q0 >> 32)),
                             __uint_as_float((unsigned)q1), __uint_as_float((unsigned)(q1 >> 32)) };
                uvb = f32x4{ __uint_as_float((unsigned)q2), __uint_as_float((unsigned)(q2 >> 32)),
                             __uint_as_float((unsigned)q3), __uint_as_float((unsigned)(q3 >> 32)) };
            }
            unsigned pk[2][4];
#pragma unroll
            for (int r = 0; r < 4; ++r) {
                const float y0 = fast_tanh(ah0a[r] + ah0b[r] + uva[r]);
                const float y1 = fast_tanh(ah1a[r] + ah1b[r] + uvb[r]);
                unsigned short h0 = bf16_rne(y0), h1 = bf16_rne(y1);
                pk[0][r] = (unsigned)h0 | ((unsigned)bf16_rne(y0 - bf16_f(h0)) << 16);
                pk[1][r] = (unsigned)h1 | ((unsigned)bf16_rne(y1 - bf16_f(h1)) << 16);
            }
#pragma unroll
            for (int ni = 0; ni < 2; ++ni) {
                const int col = wv * 32 + ni * 16 + ln15;
#pragma unroll
                for (int r = 0; r < 4; ++r) {
                    const int row = ((lane >> 4) << 2) + r;
                    const int so = row * 512 + ((2 * col) ^ ((row & 7) << 4));
                    *(unsigned short*)(smem + HHI + so) = (unsigned short)(pk[ni][r] & 0xffffu);
                    *(unsigned short*)(smem + HLO + so) = (unsigned short)(pk[ni][r] >> 16);
                    if (!ship) {
                        const float y = bf16_f((unsigned short)(pk[ni][r] & 0xffffu)) +
                                        bf16_f((unsigned short)(pk[ni][r] >> 16));
                        __builtin_nontemporal_store(
                            y, out + ((size_t)(s16 * 16 + row) * TSTEPS + t) * HDIM + col);
                    }
                    if (t == TSTEPS - 1) {
                        const float y = bf16_f((unsigned short)(pk[ni][r] & 0xffffu)) +
                                        bf16_f((unsigned short)(pk[ni][r] >> 16));
                        __builtin_nontemporal_store(
                            y, hfinal + ((size_t)l * BATCH + s16 * 16 + row) * HDIM + col);
                    }
                }
            }
            if (doU)
                u_store(nxu + ((size_t)((t - 1) & 7) << 14) + ((size_t)tid << 5),
                        locC, au0, au1, bvn[0], bvn[1]);
        }

        // epilogue: ship u_{l+1}(511)
        if (ship) {
            if (tid == 64) {
                if (l < NLAYER - 2) wait_ge(fuG + 501, 1);
                else                wait_ge(fdA + 503, 1);
            }
            __syncthreads();
            f32x4 au0 = {}, au1 = {};
#define UE_KC(kc) do { \
            const int _off = ((kc) * 64 + hi16) ^ swz; \
            const short8 hh = *(const short8*)(smem + HHI + ln15 * 512 + _off); \
            const short8 hl = *(const short8*)(smem + HLO + ln15 * 512 + _off); \
            const short8 bh0 = *(const short8*)(smem + WXH + (wv * 32 + ln15) * 512 + _off); \
            const short8 bh1 = *(const short8*)(smem + WXH + (wv * 32 + 16 + ln15) * 512 + _off); \
            au0 = MFMA16(hh, bh0, au0);         au1 = MFMA16(hh, bh1, au1); \
            au0 = MFMA16(hh, wxl[0][kc], au0);  au1 = MFMA16(hh, wxl[1][kc], au1); \
            au0 = MFMA16(hl, bh0, au0);         au1 = MFMA16(hl, bh1, au1); \
        } while (0)
            UE_KC(0); UE_KC(1); UE_KC(2); UE_KC(3);
            UE_KC(4); UE_KC(5); UE_KC(6); UE_KC(7);
#undef UE_KC
            u_store(nxu + ((size_t)(511 & 7) << 14) + ((size_t)tid << 5),
                    locC, au0, au1, bvn[0], bvn[1]);
            VMDRAIN();
            __syncthreads();
            if (tid == 0) {
                AT_ST(fuNx + 510, 1);
                AT_ST(fuNx + 511, 1);
            }
        }
    } else {
        // ================= FEED (layer-0 u producer, slice s16) =================
        stage_whi_f32(Wx_w, smem, tid);
        short8 wxl[2][8];
#define FWINIT(ni, kc) do { \
        short8 _d; \
        cvt8(Wx_w + (size_t)(wv * 32 + ni * 16 + ln15) * HDIM + kc * 32 + kq, _d, wxl[ni][kc]); \
        asm volatile("" : "+v"(wxl[ni][kc])); \
    } while (0)
        FWINIT(0,0); FWINIT(0,1); FWINIT(0,2); FWINIT(0,3);
        FWINIT(0,4); FWINIT(0,5); FWINIT(0,6); FWINIT(0,7);
        FWINIT(1,0); FWINIT(1,1); FWINIT(1,2); FWINIT(1,3);
        FWINIT(1,4); FWINIT(1,5); FWINIT(1,6); FWINIT(1,7);
#undef FWINIT
        float b0[2];
#pragma unroll
        for (int ni = 0; ni < 2; ++ni) {
            const int col = wv * 32 + ni * 16 + ln15;
            b0[ni] = Wx_b[col] + Wh_b[col];
        }
        int* fuMe = fu + (size_t)s16 * TSTEPS;
        int* fuG  = fu + ((size_t)16 + s16) * TSTEPS;
        char* nxu = (char*)(u + (size_t)s16 * DEPTH * 4096);

        if (tid == 0) wait_ge(xcct + 192, NWG);
        __syncthreads();
        const int cbid = x8 + 8 * (1 + 11 * sh);
        const bool locC = (AT_LD(xcct + cbid) == (int)my_xcc + 1);

        for (int t = 0; t < TSTEPS; ++t) {
            if (tid == 0 && t >= 10) wait_ge(fuG + (t - 10), 1);
            __syncthreads();
            {
                const int tok = tokens[(s16 * 16 + srow) * TSTEPS + t];
                short8 hi, lo;
                cvt8_nt(emb + (size_t)tok * HDIM + scb * 8, hi, lo);   // nt: keep emb out of L2
                const int so = srow * 512 + ((scb * 16) ^ ((srow & 7) << 4));
                *(short8*)(smem + HHI + so) = hi;
                *(short8*)(smem + HLO + so) = lo;
            }
            __syncthreads();
            f32x4 ax0 = {}, ax1 = {};
#define FX_KC(kc) do { \
            const int _off = ((kc) * 64 + hi16) ^ swz; \
            const short8 xh = *(const short8*)(smem + HHI + ln15 * 512 + _off); \
            const short8 xl = *(const short8*)(smem + HLO + ln15 * 512 + _off); \
            const short8 bh0 = *(const short8*)(smem + WXH + (wv * 32 + ln15) * 512 + _off); \
            const short8 bh1 = *(const short8*)(smem + WXH + (wv * 32 + 16 + ln15) * 512 + _off); \
            ax0 = MFMA16(xh, bh0, ax0);         ax1 = MFMA16(xh, bh1, ax1); \
            ax0 = MFMA16(xh, wxl[0][kc], ax0);  ax1 = MFMA16(xh, wxl[1][kc], ax1); \
            ax0 = MFMA16(xl, bh0, ax0);         ax1 = MFMA16(xl, bh1, ax1); \
        } while (0)
            FX_KC(0); FX_KC(1); FX_KC(2); FX_KC(3);
            FX_KC(4); FX_KC(5); FX_KC(6); FX_KC(7);
#undef FX_KC
            u_store(nxu + ((size_t)(t & 7) << 14) + ((size_t)tid << 5),
                    locC, ax0, ax1, b0[0], b0[1]);
            VMDRAIN();
            __syncthreads();
            if (tid == 0) AT_ST(fuMe + t, 1);
        }
    }
}

// ---------- host ----------
extern "C" void kernel_launch(void* const* d_in, const int* in_sizes, int n_in,
                              void* d_out, int out_size, void* d_ws, size_t ws_size,
                              hipStream_t stream) {
    const int* tokens = (const int*)d_in[0];
    const float* hidden0 = (const float*)d_in[1];
    const float* emb = (const float*)d_in[2];
    const float* Wx_w = (const float*)d_in[3];
    const float* Wx_b = (const float*)d_in[4];
    const float* Wh_w = (const float*)d_in[5];
    const float* Wh_b = (const float*)d_in[6];
    float* out = (float*)d_out;

    char* ws = (char*)d_ws;
    size_t off = 0;
    auto carve = [&](size_t bytes) -> void* {
        void* p = ws + off;
        off = (off + bytes + 255) & ~(size_t)255;
        return p;
    };
    float* u = (float*)carve((size_t)NLAYER * 16 * DEPTH * 4096 * 4);  // 20.97 MB
    int* fu = (int*)carve((size_t)NLAYER * 16 * TSTEPS * 4);           // 327680 B
    int* fd = (int*)carve((size_t)16 * TSTEPS * 4);                    // 32768 B
    int* xcct = (int*)carve(1024);                                     // 1024 B
    (void)ws_size; (void)in_sizes; (void)n_in; (void)out_size;

    // fu, fd, xcct are contiguous 256-multiples: one memset
    hipMemsetAsync(fu, 0, (size_t)327680 + 32768 + 1024, stream);

    void* args[] = { (void*)&tokens, (void*)&hidden0, (void*)&emb,
                     (void*)&Wx_w, (void*)&Wx_b, (void*)&Wh_w, (void*)&Wh_b,
                     (void*)&u, (void*)&fu, (void*)&fd, (void*)&xcct, (void*)&out };
    hipLaunchCooperativeKernel((void*)rnn_pipe, dim3(NWG), dim3(NTHR), args, 0, stream);
}

// Round 14
// 2869.182 us; speedup vs baseline: 1.4555x; 1.4278x over previous
//
#include <hip/hip_runtime.h>

#define HDIM   256
#define NLAYER 10
#define BATCH  256
#define TSTEPS 512
#define NTHR   512
#define DEPTH  8
#define NREC   160               // 10 layers x 16 slices (M=16)
#define NWG    176               // + 16 feed wgs

typedef __attribute__((ext_vector_type(8))) short short8;
typedef __attribute__((ext_vector_type(4))) float f32x4;

// ---------- bf16 helpers ----------
__device__ __forceinline__ unsigned short bf16_rne(float f) {
    unsigned v = __float_as_uint(f);
    unsigned r = v + 0x7FFFu + ((v >> 16) & 1u);
    return (unsigned short)(r >> 16);
}
__device__ __forceinline__ float bf16_f(unsigned short b) {
    return __uint_as_float(((unsigned)b) << 16);
}
__device__ __forceinline__ float fast_tanh(float v) {
    float a = fabsf(v);
    float e = __expf(-2.0f * a);
    float r = (1.0f - e) / (1.0f + e);
    return __builtin_copysignf(r, v);
}
__device__ __forceinline__ void cvt8(const float* __restrict__ p, short8& hi, short8& lo) {
#pragma unroll
    for (int e = 0; e < 8; ++e) {
        float f = p[e];
        unsigned short h = bf16_rne(f);
        hi[e] = (short)h;
        lo[e] = (short)bf16_rne(f - bf16_f(h));
    }
}
__device__ __forceinline__ void cvt8_nt(const float* __restrict__ p, short8& hi, short8& lo) {
#pragma unroll
    for (int e = 0; e < 8; ++e) {
        float f = __builtin_nontemporal_load(p + e);
        unsigned short h = bf16_rne(f);
        hi[e] = (short)h;
        lo[e] = (short)bf16_rne(f - bf16_f(h));
    }
}

#define MFMA16(a, b, c) __builtin_amdgcn_mfma_f32_16x16x32_bf16((a), (b), (c), 0, 0, 0)

__device__ __forceinline__ void wait_ge(int* f, int need) {
    while (__hip_atomic_load(f, __ATOMIC_RELAXED, __HIP_MEMORY_SCOPE_AGENT) < need)
        __builtin_amdgcn_s_sleep(1);
}
#define AT_LD(p)    __hip_atomic_load((p), __ATOMIC_RELAXED, __HIP_MEMORY_SCOPE_AGENT)
#define AT_ST(p, v) __hip_atomic_store((p), (v), __ATOMIC_RELAXED, __HIP_MEMORY_SCOPE_AGENT)
#define VMDRAIN()   asm volatile("s_waitcnt vmcnt(0)" ::: "memory")
#define PKF(a, b)   (((unsigned long long)__float_as_uint(b) << 32) | __float_as_uint(a))

// LDS (160 KB): WXH 128KB swizzled Wx_{l+1}; two h planes (16KB: hi@0, lo@+8192)
#define WXH 0
#define HPL 131072

__device__ __forceinline__ void stage_whi_f32(const float* __restrict__ src, char* smem, int tid) {
    for (int i = 0; i < 16; ++i) {
        const int ch = tid + i * NTHR;
        const int r = ch >> 5, kb = ch & 31;
        short8 hi, lo;
        cvt8(src + (size_t)r * HDIM + kb * 8, hi, lo);
        *(short8*)(smem + r * 512 + ((kb * 16) ^ ((r & 7) << 4))) = hi;
    }
}

// ---------- producer-computes-u pipeline, single-barrier steps ----------
// Lattice (per-step flags fu[10][16][T], fd[16][T], all sc1 relaxed):
//  body t: [polls: fuMe[t+1] (RAW prefetch), fWit[t-11] (WAR)] -> barrier ->
//          publish fuNx/fdMe[t-3] -> vmcnt(0) (drains <= body t-2 stores + u(t) load)
//          -> prefetch u(t+1) -> MFMA -> tanh(u(t)) -> LDS h(t) plane^1 ; ship u(t-1).
//  publish[t-3] valid: u(t-3) stores issued body t-2, drained by body t-1's top-drain,
//  all waves attested by body-t barrier. WAR: producer body t overwrites u(t-9);
//  consumer prefetched it at body t-10, drained top-drain body t-9, attested by its
//  publish at body t-8 = index [t-11] (clamped to [0] for t in [9,11)). Feed: [t-10]/[0].
//  Epilogue: ship u(511) (slot 7 over u(503): witness [501]); publish [509..511].
__global__ void __launch_bounds__(NTHR) rnn_pipe(
    const int* __restrict__ tokens, const float* __restrict__ hidden0,
    const float* __restrict__ emb,
    const float* __restrict__ Wx_w, const float* __restrict__ Wx_b,
    const float* __restrict__ Wh_w, const float* __restrict__ Wh_b,
    float* __restrict__ u,            // [10][16][DEPTH][4096] f32, tid-linear frags
    int* __restrict__ fu,             // [10][16][TSTEPS]
    int* __restrict__ fd,             // [16][TSTEPS]
    float* __restrict__ out) {
    const int bid = blockIdx.x;
    const int tid = threadIdx.x;
    const int wv = tid >> 6;
    const int lane = tid & 63;
    const int ln15 = lane & 15;
    const int kq = (lane >> 4) << 3;
    const int hi16 = (lane >> 4) << 4;
    const int swz = (ln15 & 7) << 4;
    const int srow = tid >> 5;
    const int scb = tid & 31;

    __shared__ char smem[163840];
    float* hfinal = out + (size_t)BATCH * TSTEPS * HDIM;

    if (bid < NREC) {
        // ================= REC (layer l, slice s16) =================
        const int l = bid >> 4, s16 = bid & 15;
        const bool ship = (l < NLAYER - 1);

        if (ship) stage_whi_f32(Wx_w + (size_t)(l + 1) * 65536, smem, tid);
        short8 whh[2][8], whl[2][8], wxl[2][8];
        {
            const float* whsrc = Wh_w + (size_t)l * 65536;
            const float* wxsrc = Wx_w + (size_t)(l + 1) * 65536;
#define WINIT(ni, kc) do { \
            cvt8(whsrc + (size_t)(wv * 32 + ni * 16 + ln15) * HDIM + kc * 32 + kq, whh[ni][kc], whl[ni][kc]); \
            if (ship) { short8 _d; \
                cvt8(wxsrc + (size_t)(wv * 32 + ni * 16 + ln15) * HDIM + kc * 32 + kq, _d, wxl[ni][kc]); } \
            else { wxl[ni][kc] = short8{0,0,0,0,0,0,0,0}; } \
            asm volatile("" : "+v"(whh[ni][kc]), "+v"(whl[ni][kc]), "+v"(wxl[ni][kc])); \
        } while (0)
            WINIT(0,0); WINIT(0,1); WINIT(0,2); WINIT(0,3);
            WINIT(0,4); WINIT(0,5); WINIT(0,6); WINIT(0,7);
            WINIT(1,0); WINIT(1,1); WINIT(1,2); WINIT(1,3);
            WINIT(1,4); WINIT(1,5); WINIT(1,6); WINIT(1,7);
#undef WINIT
        }
        // h(-1) -> plane 0
        {
            short8 hi, lo;
            cvt8(hidden0 + ((size_t)(l * BATCH + s16 * 16 + srow)) * HDIM + scb * 8, hi, lo);
            const int so = srow * 512 + ((scb * 16) ^ ((srow & 7) << 4));
            *(short8*)(smem + HPL + so) = hi;
            *(short8*)(smem + HPL + 8192 + so) = lo;
        }
        float bvn[2] = { 0.f, 0.f };
        if (ship) {
#pragma unroll
            for (int ni = 0; ni < 2; ++ni) {
                const int col = wv * 32 + ni * 16 + ln15;
                bvn[ni] = Wx_b[(l + 1) * HDIM + col] + Wh_b[(l + 1) * HDIM + col];
            }
        }

        int* fuMe = fu + ((size_t)l * 16 + s16) * TSTEPS;
        int* fuNx = ship ? fu + ((size_t)(l + 1) * 16 + s16) * TSTEPS : nullptr;
        int* fWit = (l <= 7) ? fu + ((size_t)(l + 2) * 16 + s16) * TSTEPS
                             : fd + (size_t)s16 * TSTEPS;
        int* fdMe = fd + (size_t)s16 * TSTEPS;
        const unsigned long long* myu = (const unsigned long long*)
            (u + ((size_t)(l * 16 + s16)) * DEPTH * 4096);
        unsigned long long* nxu = ship ? (unsigned long long*)
            (u + ((size_t)((l + 1) * 16 + s16)) * DEPTH * 4096) : nullptr;

        __syncthreads();   // staging visible
        if (tid == 0) wait_ge(fuMe + 0, 1);
        __syncthreads();
        // prefetch u(0)
        unsigned long long qA0, qA1, qA2, qA3, qB0, qB1, qB2, qB3;
        {
            const unsigned long long* up = myu + (size_t)tid * 4;
            qA0 = AT_LD(up); qA1 = AT_LD(up + 1); qA2 = AT_LD(up + 2); qA3 = AT_LD(up + 3);
        }
        qB0 = qB1 = qB2 = qB3 = 0;

#define STEP(T, RDO, WRO, QC0, QC1, QC2, QC3, QN0, QN1, QN2, QN3) do {                    \
        if (tid == 0 && (T) + 1 < TSTEPS) wait_ge(fuMe + (T) + 1, 1);                     \
        if (tid == 64 && ship && (T) >= 9)                                                \
            wait_ge(fWit + ((T) >= 11 ? (T) - 11 : 0), 1);                                \
        __syncthreads();                                                                  \
        asm volatile("" ::: "memory");                                                    \
        if (tid == 0 && (T) >= 3) {                                                       \
            if (ship) AT_ST(fuNx + (T) - 3, 1);                                           \
            else      AT_ST(fdMe + (T) - 3, 1);                                           \
        }                                                                                 \
        VMDRAIN();                                                                        \
        __builtin_amdgcn_sched_barrier(0);                                                \
        if ((T) + 1 < TSTEPS) {                                                           \
            const unsigned long long* up_ =                                               \
                myu + (size_t)(((T) + 1) & 7) * 2048 + (size_t)tid * 4;                   \
            QN0 = AT_LD(up_);     QN1 = AT_LD(up_ + 1);                                   \
            QN2 = AT_LD(up_ + 2); QN3 = AT_LD(up_ + 3);                                   \
        }                                                                                 \
        const char* rdp = smem + HPL + (RDO);                                             \
        char* wrp = smem + HPL + (WRO);                                                   \
        const bool doU = ship && (T) >= 1;                                                \
        f32x4 ah0a = {}, ah0b = {}, ah1a = {}, ah1b = {};                                 \
        f32x4 au0 = {}, au1 = {};                                                         \
        HX_KC(0, ah0a, ah1a); HX_KC(1, ah0a, ah1a);                                       \
        HX_KC(2, ah0a, ah1a); HX_KC(3, ah0a, ah1a);                                       \
        HX_KC(4, ah0b, ah1b); HX_KC(5, ah0b, ah1b);                                       \
        HX_KC(6, ah0b, ah1b); HX_KC(7, ah0b, ah1b);                                       \
        const f32x4 uva = { __uint_as_float((unsigned)(QC0)),                             \
                            __uint_as_float((unsigned)((QC0) >> 32)),                     \
                            __uint_as_float((unsigned)(QC1)),                             \
                            __uint_as_float((unsigned)((QC1) >> 32)) };                   \
        const f32x4 uvb = { __uint_as_float((unsigned)(QC2)),                             \
                            __uint_as_float((unsigned)((QC2) >> 32)),                     \
                            __uint_as_float((unsigned)(QC3)),                             \
                            __uint_as_float((unsigned)((QC3) >> 32)) };                   \
        unsigned pk[2][4];                                                                \
        _Pragma("unroll")                                                                 \
        for (int r = 0; r < 4; ++r) {                                                     \
            const float y0 = fast_tanh(ah0a[r] + ah0b[r] + uva[r]);                       \
            const float y1 = fast_tanh(ah1a[r] + ah1b[r] + uvb[r]);                       \
            unsigned short h0 = bf16_rne(y0), h1 = bf16_rne(y1);                          \
            pk[0][r] = (unsigned)h0 | ((unsigned)bf16_rne(y0 - bf16_f(h0)) << 16);        \
            pk[1][r] = (unsigned)h1 | ((unsigned)bf16_rne(y1 - bf16_f(h1)) << 16);        \
        }                                                                                 \
        _Pragma("unroll")                                                                 \
        for (int ni = 0; ni < 2; ++ni) {                                                  \
            const int col = wv * 32 + ni * 16 + ln15;                                     \
            _Pragma("unroll")                                                             \
            for (int r = 0; r < 4; ++r) {                                                 \
                const int row = ((lane >> 4) << 2) + r;                                   \
                const int so = row * 512 + ((2 * col) ^ ((row & 7) << 4));                \
                *(unsigned short*)(wrp + so) = (unsigned short)(pk[ni][r] & 0xffffu);     \
                *(unsigned short*)(wrp + 8192 + so) = (unsigned short)(pk[ni][r] >> 16);  \
                if (!ship) {                                                              \
                    const float y = bf16_f((unsigned short)(pk[ni][r] & 0xffffu)) +       \
                                    bf16_f((unsigned short)(pk[ni][r] >> 16));            \
                    __builtin_nontemporal_store(                                          \
                        y, out + ((size_t)(s16 * 16 + row) * TSTEPS + (T)) * HDIM + col); \
                }                                                                         \
                if ((T) == TSTEPS - 1) {                                                  \
                    const float y = bf16_f((unsigned short)(pk[ni][r] & 0xffffu)) +       \
                                    bf16_f((unsigned short)(pk[ni][r] >> 16));            \
                    __builtin_nontemporal_store(                                          \
                        y, hfinal + ((size_t)l * BATCH + s16 * 16 + row) * HDIM + col);   \
                }                                                                         \
            }                                                                             \
        }                                                                                 \
        if (doU) {                                                                        \
            unsigned long long* us =                                                      \
                nxu + (size_t)(((T) - 1) & 7) * 2048 + (size_t)tid * 4;                   \
            AT_ST(us + 0, PKF(au0[0] + bvn[0], au0[1] + bvn[0]));                         \
            AT_ST(us + 1, PKF(au0[2] + bvn[0], au0[3] + bvn[0]));                         \
            AT_ST(us + 2, PKF(au1[0] + bvn[1], au1[1] + bvn[1]));                         \
            AT_ST(us + 3, PKF(au1[2] + bvn[1], au1[3] + bvn[1]));                         \
        }                                                                                 \
    } while (0)

#define HX_KC(kc, A0, A1) do {                                                            \
        const int _off = ((kc) * 64 + hi16) ^ swz;                                        \
        const short8 hh = *(const short8*)(rdp + ln15 * 512 + _off);                      \
        const short8 hl = *(const short8*)(rdp + 8192 + ln15 * 512 + _off);               \
        A0 = MFMA16(hh, whh[0][kc], A0);  A1 = MFMA16(hh, whh[1][kc], A1);                \
        A0 = MFMA16(hh, whl[0][kc], A0);  A1 = MFMA16(hh, whl[1][kc], A1);                \
        A0 = MFMA16(hl, whh[0][kc], A0);  A1 = MFMA16(hl, whh[1][kc], A1);                \
        if (doU) {                                                                        \
            const short8 bh0 = *(const short8*)(smem + WXH + (wv * 32 + ln15) * 512 + _off); \
            const short8 bh1 = *(const short8*)(smem + WXH + (wv * 32 + 16 + ln15) * 512 + _off); \
            au0 = MFMA16(hh, bh0, au0);         au1 = MFMA16(hh, bh1, au1);               \
            au0 = MFMA16(hh, wxl[0][kc], au0);  au1 = MFMA16(hh, wxl[1][kc], au1);        \
            au0 = MFMA16(hl, bh0, au0);         au1 = MFMA16(hl, bh1, au1);               \
        }                                                                                 \
    } while (0)

        for (int tb = 0; tb < TSTEPS / 2; ++tb) {
            const int t0 = 2 * tb, t1 = 2 * tb + 1;
            { STEP(t0, 0, 16384, qA0, qA1, qA2, qA3, qB0, qB1, qB2, qB3); }
            { STEP(t1, 16384, 0, qB0, qB1, qB2, qB3, qA0, qA1, qA2, qA3); }
        }
#undef STEP

        // ---- epilogue: ship u_{l+1}(511) from h(511) (plane 0); publish [509..511] ----
        if (ship) {
            if (tid == 64) wait_ge(fWit + 501, 1);
            __syncthreads();
            const char* rdp = smem + HPL;
            f32x4 au0 = {}, au1 = {};
            const bool doU = true;
            HX_KC(0, au0, au1); // note: A0/A1 args unused for h-acc here; reuse macro via dummy:
            // (the HX_KC macro accumulates h@Wh into A0/A1 too, harmless — au0/au1 get extra
            //  h@Wh terms if A0==au0! So do NOT reuse; compute explicitly below instead.)
            au0 = f32x4{}; au1 = f32x4{};
#define UE_KC(kc) do {                                                                    \
            const int _off = ((kc) * 64 + hi16) ^ swz;                                    \
            const short8 hh = *(const short8*)(rdp + ln15 * 512 + _off);                  \
            const short8 hl = *(const short8*)(rdp + 8192 + ln15 * 512 + _off);           \
            const short8 bh0 = *(const short8*)(smem + WXH + (wv * 32 + ln15) * 512 + _off); \
            const short8 bh1 = *(const short8*)(smem + WXH + (wv * 32 + 16 + ln15) * 512 + _off); \
            au0 = MFMA16(hh, bh0, au0);         au1 = MFMA16(hh, bh1, au1);               \
            au0 = MFMA16(hh, wxl[0][kc], au0);  au1 = MFMA16(hh, wxl[1][kc], au1);        \
            au0 = MFMA16(hl, bh0, au0);         au1 = MFMA16(hl, bh1, au1);               \
        } while (0)
            UE_KC(0); UE_KC(1); UE_KC(2); UE_KC(3);
            UE_KC(4); UE_KC(5); UE_KC(6); UE_KC(7);
#undef UE_KC
            unsigned long long* us = nxu + (size_t)7 * 2048 + (size_t)tid * 4;
            AT_ST(us + 0, PKF(au0[0] + bvn[0], au0[1] + bvn[0]));
            AT_ST(us + 1, PKF(au0[2] + bvn[0], au0[3] + bvn[0]));
            AT_ST(us + 2, PKF(au1[0] + bvn[1], au1[1] + bvn[1]));
            AT_ST(us + 3, PKF(au1[2] + bvn[1], au1[3] + bvn[1]));
            VMDRAIN();
            __syncthreads();
            if (tid == 0) {
                AT_ST(fuNx + 509, 1);
                AT_ST(fuNx + 510, 1);
                AT_ST(fuNx + 511, 1);
            }
        }
#undef HX_KC
    } else {
        // ================= FEED (layer-0 u producer, slice s16) — r10-proven =================
        const int s16 = bid - NREC;
        stage_whi_f32(Wx_w, smem, tid);
        short8 wxl[2][8];
#define FWINIT(ni, kc) do { \
        short8 _d; \
        cvt8(Wx_w + (size_t)(wv * 32 + ni * 16 + ln15) * HDIM + kc * 32 + kq, _d, wxl[ni][kc]); \
        asm volatile("" : "+v"(wxl[ni][kc])); \
    } while (0)
        FWINIT(0,0); FWINIT(0,1); FWINIT(0,2); FWINIT(0,3);
        FWINIT(0,4); FWINIT(0,5); FWINIT(0,6); FWINIT(0,7);
        FWINIT(1,0); FWINIT(1,1); FWINIT(1,2); FWINIT(1,3);
        FWINIT(1,4); FWINIT(1,5); FWINIT(1,6); FWINIT(1,7);
#undef FWINIT
        float b0[2];
#pragma unroll
        for (int ni = 0; ni < 2; ++ni) {
            const int col = wv * 32 + ni * 16 + ln15;
            b0[ni] = Wx_b[col] + Wh_b[col];
        }
        int* fuMe = fu + (size_t)s16 * TSTEPS;
        int* fuG  = fu + ((size_t)16 + s16) * TSTEPS;   // REC 0's publish (its fuNx)
        unsigned long long* nxu = (unsigned long long*)(u + (size_t)s16 * DEPTH * 4096);
        __syncthreads();

        for (int t = 0; t < TSTEPS; ++t) {
            if (tid == 0 && t >= 8) wait_ge(fuG + (t >= 10 ? t - 10 : 0), 1);
            __syncthreads();
            {
                const int tok = tokens[(s16 * 16 + srow) * TSTEPS + t];
                short8 hi, lo;
                cvt8_nt(emb + (size_t)tok * HDIM + scb * 8, hi, lo);
                const int so = srow * 512 + ((scb * 16) ^ ((srow & 7) << 4));
                *(short8*)(smem + HPL + so) = hi;
                *(short8*)(smem + HPL + 8192 + so) = lo;
            }
            __syncthreads();
            f32x4 ax0 = {}, ax1 = {};
#define FX_KC(kc) do { \
            const int _off = ((kc) * 64 + hi16) ^ swz; \
            const short8 xh = *(const short8*)(smem + HPL + ln15 * 512 + _off); \
            const short8 xl = *(const short8*)(smem + HPL + 8192 + ln15 * 512 + _off); \
            const short8 bh0 = *(const short8*)(smem + WXH + (wv * 32 + ln15) * 512 + _off); \
            const short8 bh1 = *(const short8*)(smem + WXH + (wv * 32 + 16 + ln15) * 512 + _off); \
            ax0 = MFMA16(xh, bh0, ax0);         ax1 = MFMA16(xh, bh1, ax1); \
            ax0 = MFMA16(xh, wxl[0][kc], ax0);  ax1 = MFMA16(xh, wxl[1][kc], ax1); \
            ax0 = MFMA16(xl, bh0, ax0);         ax1 = MFMA16(xl, bh1, ax1); \
        } while (0)
            FX_KC(0); FX_KC(1); FX_KC(2); FX_KC(3);
            FX_KC(4); FX_KC(5); FX_KC(6); FX_KC(7);
#undef FX_KC
            unsigned long long* us = nxu + (size_t)(t & 7) * 2048 + (size_t)tid * 4;
            AT_ST(us + 0, PKF(ax0[0] + b0[0], ax0[1] + b0[0]));
            AT_ST(us + 1, PKF(ax0[2] + b0[0], ax0[3] + b0[0]));
            AT_ST(us + 2, PKF(ax1[0] + b0[1], ax1[1] + b0[1]));
            AT_ST(us + 3, PKF(ax1[2] + b0[1], ax1[3] + b0[1]));
            VMDRAIN();
            __syncthreads();
            if (tid == 0) AT_ST(fuMe + t, 1);
        }
    }
}

// ---------- host ----------
extern "C" void kernel_launch(void* const* d_in, const int* in_sizes, int n_in,
                              void* d_out, int out_size, void* d_ws, size_t ws_size,
                              hipStream_t stream) {
    const int* tokens = (const int*)d_in[0];
    const float* hidden0 = (const float*)d_in[1];
    const float* emb = (const float*)d_in[2];
    const float* Wx_w = (const float*)d_in[3];
    const float* Wx_b = (const float*)d_in[4];
    const float* Wh_w = (const float*)d_in[5];
    const float* Wh_b = (const float*)d_in[6];
    float* out = (float*)d_out;

    char* ws = (char*)d_ws;
    size_t off = 0;
    auto carve = [&](size_t bytes) -> void* {
        void* p = ws + off;
        off = (off + bytes + 255) & ~(size_t)255;
        return p;
    };
    float* u = (float*)carve((size_t)NLAYER * 16 * DEPTH * 4096 * 4);  // 20.97 MB
    int* fu = (int*)carve((size_t)NLAYER * 16 * TSTEPS * 4);           // 327680 B
    int* fd = (int*)carve((size_t)16 * TSTEPS * 4);                    // 32768 B
    (void)ws_size; (void)in_sizes; (void)n_in; (void)out_size;

    hipMemsetAsync(fu, 0, (size_t)327680 + 32768, stream);             // fu+fd contiguous

    void* args[] = { (void*)&tokens, (void*)&hidden0, (void*)&emb,
                     (void*)&Wx_w, (void*)&Wx_b, (void*)&Wh_w, (void*)&Wh_b,
                     (void*)&u, (void*)&fu, (void*)&fd, (void*)&out };
    hipLaunchCooperativeKernel((void*)rnn_pipe, dim3(NWG), dim3(NTHR), args, 0, stream);
}